// Round 1
// baseline (714.326 us; speedup 1.0000x reference)
//
#include <hip/hip_runtime.h>
#include <hip/hip_bf16.h>

// Bahdanau attention, MI355X. B=32, T=2048, D=1024, U=1024.
// Pipeline: init -> W1 transpose/bf16 -> projq(q@W2+b1+b2) -> fused
// score GEMM (bf16 MFMA + tanh·V epilogue) -> softmax -> context.

typedef __bf16 bf16x8 __attribute__((ext_vector_type(8)));
typedef __bf16 bf16x4 __attribute__((ext_vector_type(4)));
typedef float  f32x4  __attribute__((ext_vector_type(4)));

#define B_  32
#define T_  2048
#define D_  1024
#define U_  1024

// ws layout (bytes)
#define WS_W1T    ((size_t)0)                        // 2 MiB bf16 [U][D]
#define WS_PROJQ  ((size_t)(2u*1024*1024))           // 128 KiB fp32 [B][U]
#define WS_SCORE  ((size_t)(2u*1024*1024 + 128u*1024)) // 256 KiB fp32 [B*T]

// ---------------- init: projq = b1+b2 (broadcast), score = 0 ----------------
__global__ void init_kernel(const float* __restrict__ b1, const float* __restrict__ b2,
                            float* __restrict__ projq, float* __restrict__ score) {
    int i = blockIdx.x * 256 + threadIdx.x;       // grid 384*256 = 98304 exact
    if (i < B_ * U_) {
        projq[i] = b1[i & (U_ - 1)] + b2[i & (U_ - 1)];
    } else {
        score[i - B_ * U_] = 0.0f;
    }
}

// ---------------- W1 [D][U] fp32 -> W1T [U][D] bf16 ----------------
__global__ void w1_transpose_kernel(const float* __restrict__ W1, __bf16* __restrict__ W1T) {
    __shared__ float tile[64][65];
    const int bx = blockIdx.x & 15;   // u tile
    const int by = blockIdx.x >> 4;   // d tile
    const int tid = threadIdx.x;      // 256
    const int j  = tid & 63;
    const int i0 = tid >> 6;          // 0..3
#pragma unroll
    for (int p = 0; p < 16; ++p) {
        const int i = i0 + p * 4;
        tile[i][j] = W1[(size_t)(by * 64 + i) * U_ + bx * 64 + j];
    }
    __syncthreads();
#pragma unroll
    for (int p = 0; p < 16; ++p) {
        const int i = i0 + p * 4;     // local u row
        W1T[(size_t)(bx * 64 + i) * D_ + by * 64 + j] = (__bf16)tile[j][i];
    }
}

// ---------------- projq += query @ W2 (fp32, d-split + atomics) ----------------
__global__ void projq_kernel(const float* __restrict__ query, const float* __restrict__ W2,
                             float* __restrict__ projq) {
    __shared__ float q[128];
    const int b  = blockIdx.x >> 3;   // 32
    const int dc = blockIdx.x & 7;    // 8 chunks of 128 d
    const int tid = threadIdx.x;      // 256
    if (tid < 128) q[tid] = query[(size_t)b * D_ + dc * 128 + tid];
    __syncthreads();
    const int u0 = tid * 4;
    float a0 = 0.f, a1 = 0.f, a2 = 0.f, a3 = 0.f;
    for (int d = 0; d < 128; ++d) {
        const float4 w = *(const float4*)(W2 + (size_t)(dc * 128 + d) * U_ + u0);
        const float qd = q[d];
        a0 = fmaf(qd, w.x, a0); a1 = fmaf(qd, w.y, a1);
        a2 = fmaf(qd, w.z, a2); a3 = fmaf(qd, w.w, a3);
    }
    float* p = projq + (size_t)b * U_ + u0;
    atomicAdd(p + 0, a0); atomicAdd(p + 1, a1);
    atomicAdd(p + 2, a2); atomicAdd(p + 3, a3);
}

// ---------------- fused score GEMM ----------------
// grid 2048: blockIdx = (rowblk<<1)|nhalf. Block: 64 bt-rows x 512 u-cols.
// 512 threads = 8 waves, wave tile [64 x 64], mfma_f32_16x16x32_bf16.
__global__ __launch_bounds__(512, 2)
void score_kernel(const float* __restrict__ values, const __bf16* __restrict__ W1T,
                  const float* __restrict__ projq, const float* __restrict__ V,
                  float* __restrict__ score) {
    // +8 pad -> row stride 80 B: 16B-aligned, 20-bank stride => 2-way (free)
    __shared__ __attribute__((aligned(16))) __bf16 Al[64][40];
    __shared__ __attribute__((aligned(16))) __bf16 Bl[512][40];

    const int tid    = threadIdx.x;
    const int rowblk = blockIdx.x >> 1;
    const int nhalf  = blockIdx.x & 1;
    const int wave = tid >> 6, lane = tid & 63;
    const int quad = lane >> 4, l15 = lane & 15;

    const float*  Abase = values + (size_t)rowblk * 64 * D_;
    const __bf16* Bbase = W1T + (size_t)nhalf * 512 * D_;

    const int ar = tid >> 3;         // 0..63
    const int ac = (tid & 7) * 4;    // 0..28
    const int br = tid >> 2;         // 0..127
    const int bc = (tid & 3) * 8;    // 0..24

    f32x4 acc[4][4];
#pragma unroll
    for (int i = 0; i < 4; ++i)
#pragma unroll
        for (int j = 0; j < 4; ++j) {
            f32x4 z = {0.f, 0.f, 0.f, 0.f};
            acc[i][j] = z;
        }

    for (int kk = 0; kk < D_; kk += 32) {
        // stage A: values 64x32 fp32 -> bf16
        {
            const float4 v = *(const float4*)(Abase + (size_t)ar * D_ + kk + ac);
            bf16x4 h;
            h[0] = (__bf16)v.x; h[1] = (__bf16)v.y; h[2] = (__bf16)v.z; h[3] = (__bf16)v.w;
            *(bf16x4*)(&Al[ar][ac]) = h;
        }
        // stage B: W1T 512x32 bf16 (already converted)
#pragma unroll
        for (int p = 0; p < 4; ++p) {
            const int rr = p * 128 + br;
            const bf16x8 w = *(const bf16x8*)(Bbase + (size_t)rr * D_ + kk + bc);
            *(bf16x8*)(&Bl[rr][bc]) = w;
        }
        __syncthreads();

        bf16x8 af[4];
#pragma unroll
        for (int mt = 0; mt < 4; ++mt)
            af[mt] = *(const bf16x8*)(&Al[mt * 16 + l15][quad * 8]);
#pragma unroll
        for (int nt = 0; nt < 4; ++nt) {
            const bf16x8 bfr = *(const bf16x8*)(&Bl[wave * 64 + nt * 16 + l15][quad * 8]);
#pragma unroll
            for (int mt = 0; mt < 4; ++mt)
                acc[mt][nt] = __builtin_amdgcn_mfma_f32_16x16x32_bf16(af[mt], bfr, acc[mt][nt], 0, 0, 0);
        }
        __syncthreads();
    }

    // epilogue: partial score = sum_u tanh(acc + projq[b][u]) * V[u]
    const int b = rowblk >> 5;                 // 32 rowblks per batch
    const size_t rowbase = (size_t)rowblk * 64;
    const float* pq = projq + (size_t)b * U_;
    const int ub = nhalf * 512 + wave * 64;
#pragma unroll
    for (int mt = 0; mt < 4; ++mt) {
        float s0 = 0.f, s1 = 0.f, s2 = 0.f, s3 = 0.f;
#pragma unroll
        for (int nt = 0; nt < 4; ++nt) {
            const int u = ub + nt * 16 + l15;
            const float pqu = pq[u];
            const float vu  = V[u];
            s0 += tanhf(acc[mt][nt][0] + pqu) * vu;
            s1 += tanhf(acc[mt][nt][1] + pqu) * vu;
            s2 += tanhf(acc[mt][nt][2] + pqu) * vu;
            s3 += tanhf(acc[mt][nt][3] + pqu) * vu;
        }
        float s[4] = {s0, s1, s2, s3};
#pragma unroll
        for (int r = 0; r < 4; ++r) {
            float v = s[r];
            v += __shfl_xor(v, 1);
            v += __shfl_xor(v, 2);
            v += __shfl_xor(v, 4);
            v += __shfl_xor(v, 8);
            if (l15 == 0)
                atomicAdd(&score[rowbase + mt * 16 + quad * 4 + r], v);
        }
    }
}

// ---------------- softmax over T (masked), writes attention weights ----------------
__global__ void softmax_kernel(const float* __restrict__ score, const float* __restrict__ mask,
                               const float* __restrict__ bV, float* __restrict__ out) {
    const int b = blockIdx.x;     // 32
    const int tid = threadIdx.x;  // 256
    const float bv = bV[0];
    float s[8];
    float lmax = -3.0e38f;
#pragma unroll
    for (int i = 0; i < 8; ++i) {
        const int t = tid + i * 256;
        const float v = score[(size_t)b * T_ + t] + bv + mask[(size_t)b * T_ + t] * (-1.0e9f);
        s[i] = v;
        lmax = fmaxf(lmax, v);
    }
#pragma unroll
    for (int m = 1; m < 64; m <<= 1) lmax = fmaxf(lmax, __shfl_xor(lmax, m));
    __shared__ float redm[4], reds[4];
    if ((tid & 63) == 0) redm[tid >> 6] = lmax;
    __syncthreads();
    const float M = fmaxf(fmaxf(redm[0], redm[1]), fmaxf(redm[2], redm[3]));
    float lsum = 0.f;
#pragma unroll
    for (int i = 0; i < 8; ++i) { s[i] = __expf(s[i] - M); lsum += s[i]; }
#pragma unroll
    for (int m = 1; m < 64; m <<= 1) lsum += __shfl_xor(lsum, m);
    if ((tid & 63) == 0) reds[tid >> 6] = lsum;
    __syncthreads();
    const float inv = 1.0f / (reds[0] + reds[1] + reds[2] + reds[3]);
#pragma unroll
    for (int i = 0; i < 8; ++i)
        out[(size_t)B_ * D_ + (size_t)b * T_ + tid + i * 256] = s[i] * inv;
}

// ---------------- context = sum_t attn[b,t] * values[b,t,:] ----------------
__global__ void context_kernel(const float* __restrict__ values, const float* __restrict__ attn,
                               float* __restrict__ out) {
    const int b  = blockIdx.x >> 4;   // 32
    const int dc = blockIdx.x & 15;   // 16 chunks of 64 d
    const int tid = threadIdx.x;      // 256
    __shared__ float a[T_];
#pragma unroll
    for (int i = 0; i < 8; ++i) a[tid + i * 256] = attn[(size_t)b * T_ + tid + i * 256];
    __syncthreads();
    const int d  = dc * 64 + (tid & 63);
    const int tg = tid >> 6;
    const float* vb = values + (size_t)b * T_ * D_ + d;
    float acc = 0.f;
#pragma unroll 4
    for (int t = tg; t < T_; t += 4)
        acc = fmaf(a[t], vb[(size_t)t * D_], acc);
    __shared__ float red[4][64];
    red[tg][tid & 63] = acc;
    __syncthreads();
    if (tid < 64)
        out[(size_t)b * D_ + dc * 64 + tid] = red[0][tid] + red[1][tid] + red[2][tid] + red[3][tid];
}

extern "C" void kernel_launch(void* const* d_in, const int* in_sizes, int n_in,
                              void* d_out, int out_size, void* d_ws, size_t ws_size,
                              hipStream_t stream) {
    const float* values = (const float*)d_in[0];
    const float* query  = (const float*)d_in[1];
    const float* mask   = (const float*)d_in[2];
    const float* W1     = (const float*)d_in[3];
    const float* b1     = (const float*)d_in[4];
    const float* W2     = (const float*)d_in[5];
    const float* b2     = (const float*)d_in[6];
    const float* V      = (const float*)d_in[7];
    const float* bV     = (const float*)d_in[8];
    float* out = (float*)d_out;

    char* ws = (char*)d_ws;
    __bf16* W1T  = (__bf16*)(ws + WS_W1T);
    float*  projq = (float*)(ws + WS_PROJQ);
    float*  score = (float*)(ws + WS_SCORE);

    init_kernel<<<dim3(384), dim3(256), 0, stream>>>(b1, b2, projq, score);
    w1_transpose_kernel<<<dim3(256), dim3(256), 0, stream>>>(W1, W1T);
    projq_kernel<<<dim3(256), dim3(256), 0, stream>>>(query, W2, projq);
    score_kernel<<<dim3(2048), dim3(512), 0, stream>>>(values, W1T, projq, V, score);
    softmax_kernel<<<dim3(32), dim3(256), 0, stream>>>(score, mask, bV, out);
    context_kernel<<<dim3(512), dim3(256), 0, stream>>>(values, out + B_ * D_, out);
}

// Round 2
// 641.510 us; speedup vs baseline: 1.1135x; 1.1135x over previous
//
#include <hip/hip_runtime.h>
#include <hip/hip_bf16.h>

// Bahdanau attention, MI355X. B=32, T=2048, D=1024, U=1024.
// R2: m97-style score GEMM — values pre-converted to bf16, global_load_lds
// staging (16B), unpadded 64B-row LDS (conflict-free for b128 frag reads),
// fast tanh epilogue. Fallback to R1 fp32-staging path if ws too small.

typedef __bf16 bf16x8 __attribute__((ext_vector_type(8)));
typedef __bf16 bf16x4 __attribute__((ext_vector_type(4)));
typedef float  f32x4  __attribute__((ext_vector_type(4)));

#define B_  32
#define T_  2048
#define D_  1024
#define U_  1024
#define BT_ (B_*T_)

// ws layout (bytes)
#define WS_W1T    ((size_t)0)                          // 2 MiB bf16 [U][D]
#define WS_PROJQ  ((size_t)(2u*1024*1024))             // 128 KiB fp32 [B][U]
#define WS_SCORE  ((size_t)(2u*1024*1024 + 128u*1024)) // 256 KiB fp32 [B*T]
#define WS_VALB   ((size_t)(4u*1024*1024))             // 128 MiB bf16 [BT][D]
#define WS_NEEDED (WS_VALB + (size_t)BT_ * D_ * 2)

__device__ __forceinline__ float tanh_fast(float x) {
    // tanh(x) = 1 - 2/(exp(2x)+1); exact limits at +-inf, ~1e-7 abs err.
    const float e = __expf(2.0f * x);
    return 1.0f - __fdividef(2.0f, e + 1.0f);
}

__device__ __forceinline__ void glls16(const void* g, void* l) {
    __builtin_amdgcn_global_load_lds(
        (const __attribute__((address_space(1))) void*)g,
        (__attribute__((address_space(3))) void*)l, 16, 0, 0);
}

// ---------------- init: projq = b1+b2 (broadcast), score = 0 ----------------
__global__ void init_kernel(const float* __restrict__ b1, const float* __restrict__ b2,
                            float* __restrict__ projq, float* __restrict__ score) {
    int i = blockIdx.x * 256 + threadIdx.x;       // grid 384*256 = 98304 exact
    if (i < B_ * U_) {
        projq[i] = b1[i & (U_ - 1)] + b2[i & (U_ - 1)];
    } else {
        score[i - B_ * U_] = 0.0f;
    }
}

// ---------------- values fp32 -> bf16 (streaming) ----------------
__global__ void convert_kernel(const float* __restrict__ v, __bf16* __restrict__ o) {
    const size_t i = ((size_t)blockIdx.x * 256 + threadIdx.x) * 8;   // grid 32768
    const float4 a = *(const float4*)(v + i);
    const float4 b = *(const float4*)(v + i + 4);
    bf16x8 h;
    h[0] = (__bf16)a.x; h[1] = (__bf16)a.y; h[2] = (__bf16)a.z; h[3] = (__bf16)a.w;
    h[4] = (__bf16)b.x; h[5] = (__bf16)b.y; h[6] = (__bf16)b.z; h[7] = (__bf16)b.w;
    *(bf16x8*)(o + i) = h;
}

// ---------------- W1 [D][U] fp32 -> W1T [U][D] bf16 ----------------
__global__ void w1_transpose_kernel(const float* __restrict__ W1, __bf16* __restrict__ W1T) {
    __shared__ float tile[64][65];
    const int bx = blockIdx.x & 15;   // u tile
    const int by = blockIdx.x >> 4;   // d tile
    const int tid = threadIdx.x;      // 256
    const int j  = tid & 63;
    const int i0 = tid >> 6;          // 0..3
#pragma unroll
    for (int p = 0; p < 16; ++p) {
        const int i = i0 + p * 4;
        tile[i][j] = W1[(size_t)(by * 64 + i) * U_ + bx * 64 + j];
    }
    __syncthreads();
#pragma unroll
    for (int p = 0; p < 16; ++p) {
        const int i = i0 + p * 4;     // local u row
        W1T[(size_t)(bx * 64 + i) * D_ + by * 64 + j] = (__bf16)tile[j][i];
    }
}

// ---------------- projq += query @ W2 (fp32, d-split + atomics) ----------------
__global__ void projq_kernel(const float* __restrict__ query, const float* __restrict__ W2,
                             float* __restrict__ projq) {
    __shared__ float q[128];
    const int b  = blockIdx.x >> 3;   // 32
    const int dc = blockIdx.x & 7;    // 8 chunks of 128 d
    const int tid = threadIdx.x;      // 256
    if (tid < 128) q[tid] = query[(size_t)b * D_ + dc * 128 + tid];
    __syncthreads();
    const int u0 = tid * 4;
    float a0 = 0.f, a1 = 0.f, a2 = 0.f, a3 = 0.f;
    for (int d = 0; d < 128; ++d) {
        const float4 w = *(const float4*)(W2 + (size_t)(dc * 128 + d) * U_ + u0);
        const float qd = q[d];
        a0 = fmaf(qd, w.x, a0); a1 = fmaf(qd, w.y, a1);
        a2 = fmaf(qd, w.z, a2); a3 = fmaf(qd, w.w, a3);
    }
    float* p = projq + (size_t)b * U_ + u0;
    atomicAdd(p + 0, a0); atomicAdd(p + 1, a1);
    atomicAdd(p + 2, a2); atomicAdd(p + 3, a3);
}

// ---------------- fused score GEMM, m97 structure ----------------
// grid 4096: blockIdx = rowblk*8 + utile. 256 threads = 4 waves (2x2 of
// 64x64 wave tiles). Tile 128(bt) x 128(u), BK=32. LDS unpadded [128][32]
// bf16 (64B rows): frag-read banks disjoint per quad -> conflict-free.
__global__ __launch_bounds__(256, 3)
void score_kernel_bf16(const __bf16* __restrict__ valb, const __bf16* __restrict__ W1T,
                       const float* __restrict__ projq, const float* __restrict__ V,
                       float* __restrict__ score) {
    __shared__ __attribute__((aligned(16))) __bf16 Al[128 * 32];
    __shared__ __attribute__((aligned(16))) __bf16 Bl[128 * 32];

    const int tid = threadIdx.x;
    const int rowblk = blockIdx.x >> 3;
    const int utile  = blockIdx.x & 7;
    const int wave = tid >> 6, lane = tid & 63;
    const int quad = lane >> 4, l15 = lane & 15;
    const int wr = (wave >> 1) * 64;   // wave row offset in tile
    const int wc = (wave & 1) * 64;    // wave col offset in tile

    // staging source: thread tid covers tile row tid>>2 (+64 for 2nd load),
    // k-elems (tid&3)*8 .. +7 — matches HW dest base + lane*16.
    const __bf16* Ab = valb + ((size_t)rowblk * 128 + (tid >> 2)) * D_ + (tid & 3) * 8;
    const __bf16* Bb = W1T + ((size_t)utile * 128 + (tid >> 2)) * D_ + (tid & 3) * 8;
    __bf16* Ald = Al + wave * 512;     // wave-uniform LDS base (bytes: wave*1024)
    __bf16* Bld = Bl + wave * 512;

    f32x4 acc[4][4];
#pragma unroll
    for (int i = 0; i < 4; ++i)
#pragma unroll
        for (int j = 0; j < 4; ++j) {
            f32x4 z = {0.f, 0.f, 0.f, 0.f};
            acc[i][j] = z;
        }

    for (int kk = 0; kk < D_; kk += 32) {
        glls16(Ab + kk,            Ald);
        glls16(Ab + 64 * D_ + kk,  Ald + 2048);
        glls16(Bb + kk,            Bld);
        glls16(Bb + 64 * D_ + kk,  Bld + 2048);
        __syncthreads();

        bf16x8 af[4];
#pragma unroll
        for (int mt = 0; mt < 4; ++mt)
            af[mt] = *(const bf16x8*)(Al + (wr + mt * 16 + l15) * 32 + quad * 8);
#pragma unroll
        for (int nt = 0; nt < 4; ++nt) {
            const bf16x8 bfr = *(const bf16x8*)(Bl + (wc + nt * 16 + l15) * 32 + quad * 8);
#pragma unroll
            for (int mt = 0; mt < 4; ++mt)
                acc[mt][nt] = __builtin_amdgcn_mfma_f32_16x16x32_bf16(af[mt], bfr, acc[mt][nt], 0, 0, 0);
        }
        __syncthreads();
    }

    // epilogue: partial score = sum_u tanh(acc + projq[b][u]) * V[u]
    const int b = rowblk >> 4;                 // 16 rowblks (of 128) per batch
    const float* pq = projq + (size_t)b * U_ + utile * 128 + wc;
    const float* Vp = V + utile * 128 + wc;
    const size_t rowbase = (size_t)rowblk * 128 + wr;
#pragma unroll
    for (int mt = 0; mt < 4; ++mt) {
        float s0 = 0.f, s1 = 0.f, s2 = 0.f, s3 = 0.f;
#pragma unroll
        for (int nt = 0; nt < 4; ++nt) {
            const int u = nt * 16 + l15;
            const float pqu = pq[u];
            const float vu  = Vp[u];
            s0 += tanh_fast(acc[mt][nt][0] + pqu) * vu;
            s1 += tanh_fast(acc[mt][nt][1] + pqu) * vu;
            s2 += tanh_fast(acc[mt][nt][2] + pqu) * vu;
            s3 += tanh_fast(acc[mt][nt][3] + pqu) * vu;
        }
        float s[4] = {s0, s1, s2, s3};
#pragma unroll
        for (int r = 0; r < 4; ++r) {
            float v = s[r];
            v += __shfl_xor(v, 1);
            v += __shfl_xor(v, 2);
            v += __shfl_xor(v, 4);
            v += __shfl_xor(v, 8);
            if (l15 == 0)
                atomicAdd(&score[rowbase + mt * 16 + quad * 4 + r], v);
        }
    }
}

// ---------------- R1 fallback score GEMM (fp32 staging), if ws too small ----
__global__ __launch_bounds__(512, 2)
void score_kernel_f32(const float* __restrict__ values, const __bf16* __restrict__ W1T,
                      const float* __restrict__ projq, const float* __restrict__ V,
                      float* __restrict__ score) {
    __shared__ __attribute__((aligned(16))) __bf16 Al[64][40];
    __shared__ __attribute__((aligned(16))) __bf16 Bl[512][40];
    const int tid    = threadIdx.x;
    const int rowblk = blockIdx.x >> 1;
    const int nhalf  = blockIdx.x & 1;
    const int wave = tid >> 6, lane = tid & 63;
    const int quad = lane >> 4, l15 = lane & 15;
    const float*  Abase = values + (size_t)rowblk * 64 * D_;
    const __bf16* Bbase = W1T + (size_t)nhalf * 512 * D_;
    const int ar = tid >> 3, ac = (tid & 7) * 4;
    const int br = tid >> 2, bc = (tid & 3) * 8;
    f32x4 acc[4][4];
#pragma unroll
    for (int i = 0; i < 4; ++i)
#pragma unroll
        for (int j = 0; j < 4; ++j) { f32x4 z = {0.f,0.f,0.f,0.f}; acc[i][j] = z; }
    for (int kk = 0; kk < D_; kk += 32) {
        {
            const float4 v = *(const float4*)(Abase + (size_t)ar * D_ + kk + ac);
            bf16x4 h;
            h[0] = (__bf16)v.x; h[1] = (__bf16)v.y; h[2] = (__bf16)v.z; h[3] = (__bf16)v.w;
            *(bf16x4*)(&Al[ar][ac]) = h;
        }
#pragma unroll
        for (int p = 0; p < 4; ++p) {
            const int rr = p * 128 + br;
            const bf16x8 w = *(const bf16x8*)(Bbase + (size_t)rr * D_ + kk + bc);
            *(bf16x8*)(&Bl[rr][bc]) = w;
        }
        __syncthreads();
        bf16x8 af[4];
#pragma unroll
        for (int mt = 0; mt < 4; ++mt)
            af[mt] = *(const bf16x8*)(&Al[mt * 16 + l15][quad * 8]);
#pragma unroll
        for (int nt = 0; nt < 4; ++nt) {
            const bf16x8 bfr = *(const bf16x8*)(&Bl[wave * 64 + nt * 16 + l15][quad * 8]);
#pragma unroll
            for (int mt = 0; mt < 4; ++mt)
                acc[mt][nt] = __builtin_amdgcn_mfma_f32_16x16x32_bf16(af[mt], bfr, acc[mt][nt], 0, 0, 0);
        }
        __syncthreads();
    }
    const int b = rowblk >> 5;
    const size_t rowbase = (size_t)rowblk * 64;
    const float* pq = projq + (size_t)b * U_;
    const int ub = nhalf * 512 + wave * 64;
#pragma unroll
    for (int mt = 0; mt < 4; ++mt) {
        float s0 = 0.f, s1 = 0.f, s2 = 0.f, s3 = 0.f;
#pragma unroll
        for (int nt = 0; nt < 4; ++nt) {
            const int u = ub + nt * 16 + l15;
            const float pqu = pq[u];
            const float vu  = V[u];
            s0 += tanh_fast(acc[mt][nt][0] + pqu) * vu;
            s1 += tanh_fast(acc[mt][nt][1] + pqu) * vu;
            s2 += tanh_fast(acc[mt][nt][2] + pqu) * vu;
            s3 += tanh_fast(acc[mt][nt][3] + pqu) * vu;
        }
        float s[4] = {s0, s1, s2, s3};
#pragma unroll
        for (int r = 0; r < 4; ++r) {
            float v = s[r];
            v += __shfl_xor(v, 1);
            v += __shfl_xor(v, 2);
            v += __shfl_xor(v, 4);
            v += __shfl_xor(v, 8);
            if (l15 == 0)
                atomicAdd(&score[rowbase + mt * 16 + quad * 4 + r], v);
        }
    }
}

// ---------------- softmax over T (masked), writes attention weights ----------------
__global__ void softmax_kernel(const float* __restrict__ score, const float* __restrict__ mask,
                               const float* __restrict__ bV, float* __restrict__ out) {
    const int b = blockIdx.x;     // 32
    const int tid = threadIdx.x;  // 256
    const float bv = bV[0];
    float s[8];
    float lmax = -3.0e38f;
#pragma unroll
    for (int i = 0; i < 8; ++i) {
        const int t = tid + i * 256;
        const float v = score[(size_t)b * T_ + t] + bv + mask[(size_t)b * T_ + t] * (-1.0e9f);
        s[i] = v;
        lmax = fmaxf(lmax, v);
    }
#pragma unroll
    for (int m = 1; m < 64; m <<= 1) lmax = fmaxf(lmax, __shfl_xor(lmax, m));
    __shared__ float redm[4], reds[4];
    if ((tid & 63) == 0) redm[tid >> 6] = lmax;
    __syncthreads();
    const float M = fmaxf(fmaxf(redm[0], redm[1]), fmaxf(redm[2], redm[3]));
    float lsum = 0.f;
#pragma unroll
    for (int i = 0; i < 8; ++i) { s[i] = __expf(s[i] - M); lsum += s[i]; }
#pragma unroll
    for (int m = 1; m < 64; m <<= 1) lsum += __shfl_xor(lsum, m);
    if ((tid & 63) == 0) reds[tid >> 6] = lsum;
    __syncthreads();
    const float inv = 1.0f / (reds[0] + reds[1] + reds[2] + reds[3]);
#pragma unroll
    for (int i = 0; i < 8; ++i)
        out[(size_t)B_ * D_ + (size_t)b * T_ + tid + i * 256] = s[i] * inv;
}

// ---------------- context = sum_t attn[b,t] * values[b,t,:] ----------------
__global__ void context_kernel(const float* __restrict__ values, const float* __restrict__ attn,
                               float* __restrict__ out) {
    const int b  = blockIdx.x >> 4;   // 32
    const int dc = blockIdx.x & 15;   // 16 chunks of 64 d
    const int tid = threadIdx.x;      // 256
    __shared__ float a[T_];
#pragma unroll
    for (int i = 0; i < 8; ++i) a[tid + i * 256] = attn[(size_t)b * T_ + tid + i * 256];
    __syncthreads();
    const int dl = (tid & 15) * 4;    // 64 d per block, float4 per thread
    const int tg = tid >> 4;          // 0..15
    const float* vb = values + (size_t)b * T_ * D_ + dc * 64 + dl;
    f32x4 acc = {0.f, 0.f, 0.f, 0.f};
#pragma unroll 4
    for (int t = tg; t < T_; t += 16) {
        const float4 v = *(const float4*)(vb + (size_t)t * D_);
        const float w = a[t];
        acc[0] = fmaf(w, v.x, acc[0]);
        acc[1] = fmaf(w, v.y, acc[1]);
        acc[2] = fmaf(w, v.z, acc[2]);
        acc[3] = fmaf(w, v.w, acc[3]);
    }
    __shared__ __attribute__((aligned(16))) float red[16][64];
    *(f32x4*)(&red[tg][dl]) = acc;
    __syncthreads();
    if (tid < 64) {
        float s = 0.f;
#pragma unroll
        for (int g = 0; g < 16; ++g) s += red[g][tid];
        out[(size_t)b * D_ + dc * 64 + tid] = s;
    }
}

extern "C" void kernel_launch(void* const* d_in, const int* in_sizes, int n_in,
                              void* d_out, int out_size, void* d_ws, size_t ws_size,
                              hipStream_t stream) {
    const float* values = (const float*)d_in[0];
    const float* query  = (const float*)d_in[1];
    const float* mask   = (const float*)d_in[2];
    const float* W1     = (const float*)d_in[3];
    const float* b1     = (const float*)d_in[4];
    const float* W2     = (const float*)d_in[5];
    const float* b2     = (const float*)d_in[6];
    const float* V      = (const float*)d_in[7];
    const float* bV     = (const float*)d_in[8];
    float* out = (float*)d_out;

    char* ws = (char*)d_ws;
    __bf16* W1T   = (__bf16*)(ws + WS_W1T);
    float*  projq = (float*)(ws + WS_PROJQ);
    float*  score = (float*)(ws + WS_SCORE);
    __bf16* valb  = (__bf16*)(ws + WS_VALB);

    init_kernel<<<dim3(384), dim3(256), 0, stream>>>(b1, b2, projq, score);
    w1_transpose_kernel<<<dim3(256), dim3(256), 0, stream>>>(W1, W1T);
    projq_kernel<<<dim3(256), dim3(256), 0, stream>>>(query, W2, projq);
    if (ws_size >= WS_NEEDED) {
        convert_kernel<<<dim3(32768), dim3(256), 0, stream>>>(values, valb);
        score_kernel_bf16<<<dim3(4096), dim3(256), 0, stream>>>(valb, W1T, projq, V, score);
    } else {
        score_kernel_f32<<<dim3(2048), dim3(512), 0, stream>>>(values, W1T, projq, V, score);
    }
    softmax_kernel<<<dim3(32), dim3(256), 0, stream>>>(score, mask, bV, out);
    context_kernel<<<dim3(512), dim3(256), 0, stream>>>(values, out + B_ * D_, out);
}

// Round 3
// 634.803 us; speedup vs baseline: 1.1253x; 1.0106x over previous
//
#include <hip/hip_runtime.h>
#include <hip/hip_bf16.h>

// Bahdanau attention, MI355X. B=32, T=2048, D=1024, U=1024.
// R3: XCD-aware swizzle in score GEMM — the 8 utile-blocks sharing one
// A-rowblk now land on the same XCD, temporally adjacent, so the A-tile is
// fetched from HBM once and re-read from that XCD's L2 (R2 showed 530 MB
// FETCH = 4x A over-fetch from cross-XCD scatter).

typedef __bf16 bf16x8 __attribute__((ext_vector_type(8)));
typedef __bf16 bf16x4 __attribute__((ext_vector_type(4)));
typedef float  f32x4  __attribute__((ext_vector_type(4)));

#define B_  32
#define T_  2048
#define D_  1024
#define U_  1024
#define BT_ (B_*T_)

// ws layout (bytes)
#define WS_W1T    ((size_t)0)                          // 2 MiB bf16 [U][D]
#define WS_PROJQ  ((size_t)(2u*1024*1024))             // 128 KiB fp32 [B][U]
#define WS_SCORE  ((size_t)(2u*1024*1024 + 128u*1024)) // 256 KiB fp32 [B*T]
#define WS_VALB   ((size_t)(4u*1024*1024))             // 128 MiB bf16 [BT][D]
#define WS_NEEDED (WS_VALB + (size_t)BT_ * D_ * 2)

__device__ __forceinline__ float tanh_fast(float x) {
    const float e = __expf(2.0f * x);
    return 1.0f - __fdividef(2.0f, e + 1.0f);
}

__device__ __forceinline__ void glls16(const void* g, void* l) {
    __builtin_amdgcn_global_load_lds(
        (const __attribute__((address_space(1))) void*)g,
        (__attribute__((address_space(3))) void*)l, 16, 0, 0);
}

// ---------------- init: projq = b1+b2 (broadcast), score = 0 ----------------
__global__ void init_kernel(const float* __restrict__ b1, const float* __restrict__ b2,
                            float* __restrict__ projq, float* __restrict__ score) {
    int i = blockIdx.x * 256 + threadIdx.x;       // grid 384*256 = 98304 exact
    if (i < B_ * U_) {
        projq[i] = b1[i & (U_ - 1)] + b2[i & (U_ - 1)];
    } else {
        score[i - B_ * U_] = 0.0f;
    }
}

// ---------------- values fp32 -> bf16 (streaming) ----------------
__global__ void convert_kernel(const float* __restrict__ v, __bf16* __restrict__ o) {
    const size_t i = ((size_t)blockIdx.x * 256 + threadIdx.x) * 8;   // grid 32768
    const float4 a = *(const float4*)(v + i);
    const float4 b = *(const float4*)(v + i + 4);
    bf16x8 h;
    h[0] = (__bf16)a.x; h[1] = (__bf16)a.y; h[2] = (__bf16)a.z; h[3] = (__bf16)a.w;
    h[4] = (__bf16)b.x; h[5] = (__bf16)b.y; h[6] = (__bf16)b.z; h[7] = (__bf16)b.w;
    *(bf16x8*)(o + i) = h;
}

// ---------------- W1 [D][U] fp32 -> W1T [U][D] bf16 ----------------
__global__ void w1_transpose_kernel(const float* __restrict__ W1, __bf16* __restrict__ W1T) {
    __shared__ float tile[64][65];
    const int bx = blockIdx.x & 15;   // u tile
    const int by = blockIdx.x >> 4;   // d tile
    const int tid = threadIdx.x;      // 256
    const int j  = tid & 63;
    const int i0 = tid >> 6;          // 0..3
#pragma unroll
    for (int p = 0; p < 16; ++p) {
        const int i = i0 + p * 4;
        tile[i][j] = W1[(size_t)(by * 64 + i) * U_ + bx * 64 + j];
    }
    __syncthreads();
#pragma unroll
    for (int p = 0; p < 16; ++p) {
        const int i = i0 + p * 4;     // local u row
        W1T[(size_t)(bx * 64 + i) * D_ + by * 64 + j] = (__bf16)tile[j][i];
    }
}

// ---------------- projq += query @ W2 (fp32, d-split + atomics) ----------------
__global__ void projq_kernel(const float* __restrict__ query, const float* __restrict__ W2,
                             float* __restrict__ projq) {
    __shared__ float q[128];
    const int b  = blockIdx.x >> 3;   // 32
    const int dc = blockIdx.x & 7;    // 8 chunks of 128 d
    const int tid = threadIdx.x;      // 256
    if (tid < 128) q[tid] = query[(size_t)b * D_ + dc * 128 + tid];
    __syncthreads();
    const int u0 = tid * 4;
    float a0 = 0.f, a1 = 0.f, a2 = 0.f, a3 = 0.f;
    for (int d = 0; d < 128; ++d) {
        const float4 w = *(const float4*)(W2 + (size_t)(dc * 128 + d) * U_ + u0);
        const float qd = q[d];
        a0 = fmaf(qd, w.x, a0); a1 = fmaf(qd, w.y, a1);
        a2 = fmaf(qd, w.z, a2); a3 = fmaf(qd, w.w, a3);
    }
    float* p = projq + (size_t)b * U_ + u0;
    atomicAdd(p + 0, a0); atomicAdd(p + 1, a1);
    atomicAdd(p + 2, a2); atomicAdd(p + 3, a3);
}

// ---------------- fused score GEMM, m97 structure + XCD swizzle ----------------
// grid 4096. XCD-aware remap: xcd = blk&7, slot = blk>>3;
// rowblk = xcd*64 + (slot>>3), utile = slot&7 — the 8 blocks sharing an
// A-rowblk are co-XCD and temporally adjacent -> A fetched once into L2.
// 256 threads = 4 waves (2x2 of 64x64 wave tiles). Tile 128(bt) x 128(u),
// BK=32. LDS unpadded [128][32] bf16: wave b128 frag-read covers a
// contiguous 1 KiB region -> bank-clean.
__global__ __launch_bounds__(256, 4)
void score_kernel_bf16(const __bf16* __restrict__ valb, const __bf16* __restrict__ W1T,
                       const float* __restrict__ projq, const float* __restrict__ V,
                       float* __restrict__ score) {
    __shared__ __attribute__((aligned(16))) __bf16 Al[128 * 32];
    __shared__ __attribute__((aligned(16))) __bf16 Bl[128 * 32];

    const int tid = threadIdx.x;
    const int xcd  = blockIdx.x & 7;
    const int slot = blockIdx.x >> 3;
    const int rowblk = xcd * 64 + (slot >> 3);
    const int utile  = slot & 7;
    const int wave = tid >> 6, lane = tid & 63;
    const int quad = lane >> 4, l15 = lane & 15;
    const int wr = (wave >> 1) * 64;   // wave row offset in tile
    const int wc = (wave & 1) * 64;    // wave col offset in tile

    // staging source: thread tid covers tile row tid>>2 (+64 for 2nd load),
    // k-elems (tid&3)*8 .. +7 — matches HW dest base + lane*16.
    const __bf16* Ab = valb + ((size_t)rowblk * 128 + (tid >> 2)) * D_ + (tid & 3) * 8;
    const __bf16* Bb = W1T + ((size_t)utile * 128 + (tid >> 2)) * D_ + (tid & 3) * 8;
    __bf16* Ald = Al + wave * 512;     // wave-uniform LDS base (bytes: wave*1024)
    __bf16* Bld = Bl + wave * 512;

    f32x4 acc[4][4];
#pragma unroll
    for (int i = 0; i < 4; ++i)
#pragma unroll
        for (int j = 0; j < 4; ++j) {
            f32x4 z = {0.f, 0.f, 0.f, 0.f};
            acc[i][j] = z;
        }

    for (int kk = 0; kk < D_; kk += 32) {
        glls16(Ab + kk,            Ald);
        glls16(Ab + 64 * D_ + kk,  Ald + 2048);
        glls16(Bb + kk,            Bld);
        glls16(Bb + 64 * D_ + kk,  Bld + 2048);
        __syncthreads();

        bf16x8 af[4];
#pragma unroll
        for (int mt = 0; mt < 4; ++mt)
            af[mt] = *(const bf16x8*)(Al + (wr + mt * 16 + l15) * 32 + quad * 8);
#pragma unroll
        for (int nt = 0; nt < 4; ++nt) {
            const bf16x8 bfr = *(const bf16x8*)(Bl + (wc + nt * 16 + l15) * 32 + quad * 8);
#pragma unroll
            for (int mt = 0; mt < 4; ++mt)
                acc[mt][nt] = __builtin_amdgcn_mfma_f32_16x16x32_bf16(af[mt], bfr, acc[mt][nt], 0, 0, 0);
        }
        __syncthreads();
    }

    // epilogue: partial score = sum_u tanh(acc + projq[b][u]) * V[u]
    const int b = rowblk >> 4;                 // 16 rowblks (of 128) per batch
    const float* pq = projq + (size_t)b * U_ + utile * 128 + wc;
    const float* Vp = V + utile * 128 + wc;
    const size_t rowbase = (size_t)rowblk * 128 + wr;
#pragma unroll
    for (int mt = 0; mt < 4; ++mt) {
        float s0 = 0.f, s1 = 0.f, s2 = 0.f, s3 = 0.f;
#pragma unroll
        for (int nt = 0; nt < 4; ++nt) {
            const int u = nt * 16 + l15;
            const float pqu = pq[u];
            const float vu  = Vp[u];
            s0 += tanh_fast(acc[mt][nt][0] + pqu) * vu;
            s1 += tanh_fast(acc[mt][nt][1] + pqu) * vu;
            s2 += tanh_fast(acc[mt][nt][2] + pqu) * vu;
            s3 += tanh_fast(acc[mt][nt][3] + pqu) * vu;
        }
        float s[4] = {s0, s1, s2, s3};
#pragma unroll
        for (int r = 0; r < 4; ++r) {
            float v = s[r];
            v += __shfl_xor(v, 1);
            v += __shfl_xor(v, 2);
            v += __shfl_xor(v, 4);
            v += __shfl_xor(v, 8);
            if (l15 == 0)
                atomicAdd(&score[rowbase + mt * 16 + quad * 4 + r], v);
        }
    }
}

// ---------------- R1 fallback score GEMM (fp32 staging), if ws too small ----
__global__ __launch_bounds__(512, 2)
void score_kernel_f32(const float* __restrict__ values, const __bf16* __restrict__ W1T,
                      const float* __restrict__ projq, const float* __restrict__ V,
                      float* __restrict__ score) {
    __shared__ __attribute__((aligned(16))) __bf16 Al[64][40];
    __shared__ __attribute__((aligned(16))) __bf16 Bl[512][40];
    const int tid    = threadIdx.x;
    const int rowblk = blockIdx.x >> 1;
    const int nhalf  = blockIdx.x & 1;
    const int wave = tid >> 6, lane = tid & 63;
    const int quad = lane >> 4, l15 = lane & 15;
    const float*  Abase = values + (size_t)rowblk * 64 * D_;
    const __bf16* Bbase = W1T + (size_t)nhalf * 512 * D_;
    const int ar = tid >> 3, ac = (tid & 7) * 4;
    const int br = tid >> 2, bc = (tid & 3) * 8;
    f32x4 acc[4][4];
#pragma unroll
    for (int i = 0; i < 4; ++i)
#pragma unroll
        for (int j = 0; j < 4; ++j) { f32x4 z = {0.f,0.f,0.f,0.f}; acc[i][j] = z; }
    for (int kk = 0; kk < D_; kk += 32) {
        {
            const float4 v = *(const float4*)(Abase + (size_t)ar * D_ + kk + ac);
            bf16x4 h;
            h[0] = (__bf16)v.x; h[1] = (__bf16)v.y; h[2] = (__bf16)v.z; h[3] = (__bf16)v.w;
            *(bf16x4*)(&Al[ar][ac]) = h;
        }
#pragma unroll
        for (int p = 0; p < 4; ++p) {
            const int rr = p * 128 + br;
            const bf16x8 w = *(const bf16x8*)(Bbase + (size_t)rr * D_ + kk + bc);
            *(bf16x8*)(&Bl[rr][bc]) = w;
        }
        __syncthreads();
        bf16x8 af[4];
#pragma unroll
        for (int mt = 0; mt < 4; ++mt)
            af[mt] = *(const bf16x8*)(&Al[mt * 16 + l15][quad * 8]);
#pragma unroll
        for (int nt = 0; nt < 4; ++nt) {
            const bf16x8 bfr = *(const bf16x8*)(&Bl[wave * 64 + nt * 16 + l15][quad * 8]);
#pragma unroll
            for (int mt = 0; mt < 4; ++mt)
                acc[mt][nt] = __builtin_amdgcn_mfma_f32_16x16x32_bf16(af[mt], bfr, acc[mt][nt], 0, 0, 0);
        }
        __syncthreads();
    }
    const int b = rowblk >> 5;
    const size_t rowbase = (size_t)rowblk * 64;
    const float* pq = projq + (size_t)b * U_;
    const int ub = nhalf * 512 + wave * 64;
#pragma unroll
    for (int mt = 0; mt < 4; ++mt) {
        float s0 = 0.f, s1 = 0.f, s2 = 0.f, s3 = 0.f;
#pragma unroll
        for (int nt = 0; nt < 4; ++nt) {
            const int u = ub + nt * 16 + l15;
            const float pqu = pq[u];
            const float vu  = V[u];
            s0 += tanh_fast(acc[mt][nt][0] + pqu) * vu;
            s1 += tanh_fast(acc[mt][nt][1] + pqu) * vu;
            s2 += tanh_fast(acc[mt][nt][2] + pqu) * vu;
            s3 += tanh_fast(acc[mt][nt][3] + pqu) * vu;
        }
        float s[4] = {s0, s1, s2, s3};
#pragma unroll
        for (int r = 0; r < 4; ++r) {
            float v = s[r];
            v += __shfl_xor(v, 1);
            v += __shfl_xor(v, 2);
            v += __shfl_xor(v, 4);
            v += __shfl_xor(v, 8);
            if (l15 == 0)
                atomicAdd(&score[rowbase + mt * 16 + quad * 4 + r], v);
        }
    }
}

// ---------------- softmax over T (masked), writes attention weights ----------------
__global__ void softmax_kernel(const float* __restrict__ score, const float* __restrict__ mask,
                               const float* __restrict__ bV, float* __restrict__ out) {
    const int b = blockIdx.x;     // 32
    const int tid = threadIdx.x;  // 256
    const float bv = bV[0];
    float s[8];
    float lmax = -3.0e38f;
#pragma unroll
    for (int i = 0; i < 8; ++i) {
        const int t = tid + i * 256;
        const float v = score[(size_t)b * T_ + t] + bv + mask[(size_t)b * T_ + t] * (-1.0e9f);
        s[i] = v;
        lmax = fmaxf(lmax, v);
    }
#pragma unroll
    for (int m = 1; m < 64; m <<= 1) lmax = fmaxf(lmax, __shfl_xor(lmax, m));
    __shared__ float redm[4], reds[4];
    if ((tid & 63) == 0) redm[tid >> 6] = lmax;
    __syncthreads();
    const float M = fmaxf(fmaxf(redm[0], redm[1]), fmaxf(redm[2], redm[3]));
    float lsum = 0.f;
#pragma unroll
    for (int i = 0; i < 8; ++i) { s[i] = __expf(s[i] - M); lsum += s[i]; }
#pragma unroll
    for (int m = 1; m < 64; m <<= 1) lsum += __shfl_xor(lsum, m);
    if ((tid & 63) == 0) reds[tid >> 6] = lsum;
    __syncthreads();
    const float inv = 1.0f / (reds[0] + reds[1] + reds[2] + reds[3]);
#pragma unroll
    for (int i = 0; i < 8; ++i)
        out[(size_t)B_ * D_ + (size_t)b * T_ + tid + i * 256] = s[i] * inv;
}

// ---------------- context = sum_t attn[b,t] * values[b,t,:] ----------------
__global__ void context_kernel(const float* __restrict__ values, const float* __restrict__ attn,
                               float* __restrict__ out) {
    const int b  = blockIdx.x >> 4;   // 32
    const int dc = blockIdx.x & 15;   // 16 chunks of 64 d
    const int tid = threadIdx.x;      // 256
    __shared__ float a[T_];
#pragma unroll
    for (int i = 0; i < 8; ++i) a[tid + i * 256] = attn[(size_t)b * T_ + tid + i * 256];
    __syncthreads();
    const int dl = (tid & 15) * 4;    // 64 d per block, float4 per thread
    const int tg = tid >> 4;          // 0..15
    const float* vb = values + (size_t)b * T_ * D_ + dc * 64 + dl;
    f32x4 acc = {0.f, 0.f, 0.f, 0.f};
#pragma unroll 4
    for (int t = tg; t < T_; t += 16) {
        const float4 v = *(const float4*)(vb + (size_t)t * D_);
        const float w = a[t];
        acc[0] = fmaf(w, v.x, acc[0]);
        acc[1] = fmaf(w, v.y, acc[1]);
        acc[2] = fmaf(w, v.z, acc[2]);
        acc[3] = fmaf(w, v.w, acc[3]);
    }
    __shared__ __attribute__((aligned(16))) float red[16][64];
    *(f32x4*)(&red[tg][dl]) = acc;
    __syncthreads();
    if (tid < 64) {
        float s = 0.f;
#pragma unroll
        for (int g = 0; g < 16; ++g) s += red[g][tid];
        out[(size_t)b * D_ + dc * 64 + tid] = s;
    }
}

extern "C" void kernel_launch(void* const* d_in, const int* in_sizes, int n_in,
                              void* d_out, int out_size, void* d_ws, size_t ws_size,
                              hipStream_t stream) {
    const float* values = (const float*)d_in[0];
    const float* query  = (const float*)d_in[1];
    const float* mask   = (const float*)d_in[2];
    const float* W1     = (const float*)d_in[3];
    const float* b1     = (const float*)d_in[4];
    const float* W2     = (const float*)d_in[5];
    const float* b2     = (const float*)d_in[6];
    const float* V      = (const float*)d_in[7];
    const float* bV     = (const float*)d_in[8];
    float* out = (float*)d_out;

    char* ws = (char*)d_ws;
    __bf16* W1T   = (__bf16*)(ws + WS_W1T);
    float*  projq = (float*)(ws + WS_PROJQ);
    float*  score = (float*)(ws + WS_SCORE);
    __bf16* valb  = (__bf16*)(ws + WS_VALB);

    init_kernel<<<dim3(384), dim3(256), 0, stream>>>(b1, b2, projq, score);
    w1_transpose_kernel<<<dim3(256), dim3(256), 0, stream>>>(W1, W1T);
    projq_kernel<<<dim3(256), dim3(256), 0, stream>>>(query, W2, projq);
    if (ws_size >= WS_NEEDED) {
        convert_kernel<<<dim3(32768), dim3(256), 0, stream>>>(values, valb);
        score_kernel_bf16<<<dim3(4096), dim3(256), 0, stream>>>(valb, W1T, projq, V, score);
    } else {
        score_kernel_f32<<<dim3(2048), dim3(512), 0, stream>>>(values, W1T, projq, V, score);
    }
    softmax_kernel<<<dim3(32), dim3(256), 0, stream>>>(score, mask, bV, out);
    context_kernel<<<dim3(512), dim3(256), 0, stream>>>(values, out + B_ * D_, out);
}